// Round 1
// 2810.424 us; speedup vs baseline: 1.2189x; 1.2189x over previous
//
#include <hip/hip_runtime.h>
#include <hip/hip_fp16.h>

// DiffusionConvolution: out[b,n,o] = bias[o] + sum_{s,k,d} (A_s^k x0)[n,(d,b)] * W[(3s+k)*64+d, o]
// B=32, N=20000, D=OUT=64, K=2, E=640000 per support.
//
// R4 structure:
//   pack_x0: inp fp32 [B,N,D] -> X0 fp16 node-major [N, B*64+d] (82 MB, L3-resident)
//   per support s:
//     CSR build (ecol/eval, separate arrays, uniform SMEM loads in spmm)
//     spmm_g<half=1>: X1 = A*X0  — fp16 gather (contiguous 4 KB/edge), write X1 bf16
//     spmm_g<half=0>: X2 = A*X1  — bf16 gather, write X2 bf16
//     proj_gemm<ADD=s>: out (+)= inp*Wk0_s + X1*W_{s,1} + X2*W_{s,2} (+bias on s=0)
//   k=0 projection term still reads fp32 inp directly (exact); fp16 X0 only feeds the
//   diffusion hops, whose error is dominated by the existing bf16 X1/X2 storage.
// Workspace: X1 82 + X2 82 + edges 5.1 + ptr/counts ~0.2 + X0 82 = ~252 MB.
// ws_size guard: if X0 tail doesn't fit, fall back to R3's fp32-gather spmm1.

constexpr int B = 32;
constexpr int D = 64;
constexpr int C = B * D;   // 2048 features per node

__device__ __forceinline__ void fma4(float4& a, float s, const float4 b) {
  a.x = fmaf(s, b.x, a.x);
  a.y = fmaf(s, b.y, a.y);
  a.z = fmaf(s, b.z, a.z);
  a.w = fmaf(s, b.w, a.w);
}

__device__ __forceinline__ unsigned f2bf(float f) {
  union { float f; unsigned u; } v; v.f = f;
  return (v.u + 0x7fffu + ((v.u >> 16) & 1u)) >> 16;   // RNE
}
__device__ __forceinline__ unsigned pk(float a, float b) {
  return f2bf(a) | (f2bf(b) << 16);
}
__device__ __forceinline__ float bflo(unsigned u) { return __uint_as_float(u << 16); }
__device__ __forceinline__ float bfhi(unsigned u) { return __uint_as_float(u & 0xffff0000u); }

__device__ __forceinline__ unsigned pkh(float a, float b) {
  union { __half2 h; unsigned u; } c;
  c.h = __floats2half2_rn(a, b);
  return c.u;
}

__device__ __forceinline__ void fma8(float4& a0, float4& a1, float v, uint4 u) {
  a0.x = fmaf(v, bflo(u.x), a0.x); a0.y = fmaf(v, bfhi(u.x), a0.y);
  a0.z = fmaf(v, bflo(u.y), a0.z); a0.w = fmaf(v, bfhi(u.y), a0.w);
  a1.x = fmaf(v, bflo(u.z), a1.x); a1.y = fmaf(v, bfhi(u.z), a1.y);
  a1.z = fmaf(v, bflo(u.w), a1.z); a1.w = fmaf(v, bfhi(u.w), a1.w);
}

__device__ __forceinline__ void fma8h(float4& a0, float4& a1, float v, uint4 u) {
  union { unsigned u; __half2 h; } c0, c1, c2, c3;
  c0.u = u.x; c1.u = u.y; c2.u = u.z; c3.u = u.w;
  float2 f0 = __half22float2(c0.h);
  float2 f1 = __half22float2(c1.h);
  float2 f2 = __half22float2(c2.h);
  float2 f3 = __half22float2(c3.h);
  a0.x = fmaf(v, f0.x, a0.x); a0.y = fmaf(v, f0.y, a0.y);
  a0.z = fmaf(v, f1.x, a0.z); a0.w = fmaf(v, f1.y, a0.w);
  a1.x = fmaf(v, f2.x, a1.x); a1.y = fmaf(v, f2.y, a1.y);
  a1.z = fmaf(v, f3.x, a1.z); a1.w = fmaf(v, f3.y, a1.w);
}

// ---------------- CSR build ----------------

__global__ __launch_bounds__(256) void hist_k(const int* __restrict__ rows,
                                              int* __restrict__ counts, int E) {
  int e = blockIdx.x * 256 + threadIdx.x;
  if (e < E) atomicAdd(&counts[rows[e]], 1);
}

__global__ __launch_bounds__(256) void scan_k(const int* __restrict__ counts,
                                              int* __restrict__ row_ptr, int N) {
  __shared__ int part[256];
  int t = threadIdx.x;
  int chunk = (N + 255) >> 8;
  int lo = t * chunk; if (lo > N) lo = N;
  int hi = lo + chunk; if (hi > N) hi = N;
  int s = 0;
  for (int i = lo; i < hi; ++i) s += counts[i];
  part[t] = s;
  __syncthreads();
  for (int off = 1; off < 256; off <<= 1) {
    int x = (t >= off) ? part[t - off] : 0;
    __syncthreads();
    part[t] += x;
    __syncthreads();
  }
  int run = part[t] - s;
  for (int i = lo; i < hi; ++i) { row_ptr[i] = run; run += counts[i]; }
  if (t == 255) row_ptr[N] = part[255];
}

__global__ __launch_bounds__(256) void fill_k(const int* __restrict__ rows,
                                              const int* __restrict__ cols,
                                              const float* __restrict__ vals,
                                              const int* __restrict__ row_ptr,
                                              int* __restrict__ cursor,
                                              int* __restrict__ ecol,
                                              float* __restrict__ eval, int E) {
  int e = blockIdx.x * 256 + threadIdx.x;
  if (e < E) {
    int r = rows[e];
    int pos = row_ptr[r] + atomicAdd(&cursor[r], 1);
    ecol[pos] = cols[e];
    eval[pos] = vals[e];
  }
}

// ---------------- pack_x0: inp fp32 [B,N,D] -> X0 fp16 node-major [N, 2048] ----------------
// One block per node n. Thread t: b = t>>3, feats 8*(t&7) .. +7 of that b.
// X0 entry index f/8 = b*8 + (t&7) = t; writes 4 KB contiguous per block.

__global__ __launch_bounds__(256) void pack_x0(const float4* __restrict__ inp4,
                                               uint4* __restrict__ X0u4, int N) {
  int n = blockIdx.x, t = threadIdx.x;
  int b = t >> 3, j = t & 7;
  const float4* p = inp4 + ((size_t)b * N + n) * 16 + j * 2;
  float4 v0 = p[0], v1 = p[1];
  X0u4[(size_t)n * 256 + t] = make_uint4(pkh(v0.x, v0.y), pkh(v0.z, v0.w),
                                         pkh(v1.x, v1.y), pkh(v1.z, v1.w));
}

// ---------------- spmm_g: D = A * S, 16-bit gather (fp16 or bf16), bf16 write ----------------
// One block per row n. Thread t owns feats 8t..8t+7 (one uint4 per edge).
// 4-deep edge unroll: 4 independent 16 B loads in flight per thread (latency-bound kernel).

template <bool HALF>
__global__ __launch_bounds__(256) void spmm_g(const uint4* __restrict__ Su4,
                                              const int* __restrict__ row_ptr,
                                              const int* __restrict__ ecol,
                                              const float* __restrict__ eval,
                                              uint4* __restrict__ Du4, int N) {
  int t = threadIdx.x;
  int n = blockIdx.x;
  float4 acc0 = {0.f, 0.f, 0.f, 0.f};
  float4 acc1 = {0.f, 0.f, 0.f, 0.f};
  int start = row_ptr[n], end = row_ptr[n + 1];
  const uint4* sp = Su4 + t;
  int e = start;
  for (; e + 4 <= end; e += 4) {
    int c0 = ecol[e], c1 = ecol[e + 1], c2 = ecol[e + 2], c3 = ecol[e + 3];
    float v0 = eval[e], v1 = eval[e + 1], v2 = eval[e + 2], v3 = eval[e + 3];
    uint4 u0 = sp[(size_t)c0 * 256];
    uint4 u1 = sp[(size_t)c1 * 256];
    uint4 u2 = sp[(size_t)c2 * 256];
    uint4 u3 = sp[(size_t)c3 * 256];
    if (HALF) {
      fma8h(acc0, acc1, v0, u0); fma8h(acc0, acc1, v1, u1);
      fma8h(acc0, acc1, v2, u2); fma8h(acc0, acc1, v3, u3);
    } else {
      fma8(acc0, acc1, v0, u0); fma8(acc0, acc1, v1, u1);
      fma8(acc0, acc1, v2, u2); fma8(acc0, acc1, v3, u3);
    }
  }
  for (; e < end; ++e) {
    uint4 u = sp[(size_t)ecol[e] * 256];
    if (HALF) fma8h(acc0, acc1, eval[e], u);
    else      fma8(acc0, acc1, eval[e], u);
  }
  Du4[(size_t)n * 256 + t] = make_uint4(pk(acc0.x, acc0.y), pk(acc0.z, acc0.w),
                                        pk(acc1.x, acc1.y), pk(acc1.z, acc1.w));
}

// ---------------- spmm1 (fallback): X1 = A * x0, fp32 gather from inp, bf16 write ----------------
// Used only if ws_size can't hold X0. One block per row n.

__global__ __launch_bounds__(256) void spmm1(const float4* __restrict__ inp4,
                                             const int* __restrict__ row_ptr,
                                             const int* __restrict__ ecol,
                                             const float* __restrict__ eval,
                                             uint2* __restrict__ X1u2, int N) {
  int t = threadIdx.x;
  int n = blockIdx.x;
  float4 acc0 = {0.f, 0.f, 0.f, 0.f};
  float4 acc1 = {0.f, 0.f, 0.f, 0.f};
  int start = row_ptr[n], end = row_ptr[n + 1];
  const float4* p0 = inp4 + (size_t)(t >> 4) * (N * 16) + (t & 15);
  const float4* p1 = inp4 + (size_t)((t >> 4) + 16) * (N * 16) + (t & 15);
  for (int e = start; e < end; ++e) {
    int col = ecol[e];
    float v = eval[e];
    fma4(acc0, v, p0[(size_t)col * 16]);
    fma4(acc1, v, p1[(size_t)col * 16]);
  }
  size_t idx = (size_t)n * 512 + (t >> 4) * 16 + (t & 15);
  X1u2[idx]       = make_uint2(pk(acc0.x, acc0.y), pk(acc0.z, acc0.w));
  X1u2[idx + 256] = make_uint2(pk(acc1.x, acc1.y), pk(acc1.z, acc1.w));
}

// ---------------- proj_gemm: out (+)= inp*Wk0 + X1*W1 + X2*W2 (+bias) ----------------
// grid ((N+63)/64, B), block 256. Tile 64n x 64o, thread tile 2n x 8o.
// Sources looped through one sA buffer; W slices via sW. LDS 16.6+16 = 32.6 KB.

template <bool ADD>
__global__ __launch_bounds__(256) void proj_gemm(const float4* __restrict__ inp4,
                                                 const uint2* __restrict__ X1u2,
                                                 const uint2* __restrict__ X2u2,
                                                 const float4* __restrict__ W4,
                                                 int w_row0,   // 192*s: W rows (w_row0 + j*64 + d)
                                                 const float4* __restrict__ bias4,
                                                 float4* __restrict__ out4, int N) {
  __shared__ float sA[64 * 65];
  __shared__ float4 sW[64 * 16];
  int t = threadIdx.x;
  int b = blockIdx.y;
  int n0 = blockIdx.x * 64;

  int np = t >> 3;                  // row pair np*2, np*2+1
  int og = t & 7;                   // outs og*8..+7
  float4 a00, a01, a10, a11;
  if (ADD) {
    a00 = a01 = a10 = a11 = make_float4(0.f, 0.f, 0.f, 0.f);
  } else {
    float4 bz0 = bias4[og * 2], bz1 = bias4[og * 2 + 1];
    a00 = bz0; a01 = bz1; a10 = bz0; a11 = bz1;
  }

  for (int j = 0; j < 3; ++j) {
    // stage W slice j: rows w_row0 + j*64 + d
#pragma unroll
    for (int k = 0; k < 4; ++k) {
      int l = t + 256 * k;          // d = l>>4, o4 = l&15
      sW[l] = W4[(size_t)(w_row0 + j * 64) * 16 + l];
    }
    // stage A tile: 64 rows x 64 d (this b)
    if (j == 0) {
#pragma unroll
      for (int k = 0; k < 4; ++k) {
        int q = t + 256 * k;
        int r = q >> 4, d4 = q & 15;
        int n = n0 + r;
        float4 v = {0.f, 0.f, 0.f, 0.f};
        if (n < N) v = inp4[((size_t)b * N + n) * 16 + d4];
        float* sp = &sA[r * 65 + d4 * 4];
        sp[0] = v.x; sp[1] = v.y; sp[2] = v.z; sp[3] = v.w;
      }
    } else {
      const uint2* Xs = (j == 1) ? X1u2 : X2u2;
#pragma unroll
      for (int k = 0; k < 4; ++k) {
        int q = t + 256 * k;
        int r = q >> 4, jj = q & 15;  // feats jj*4..+3 of (b,row)
        int n = n0 + r;
        uint2 u = make_uint2(0u, 0u);
        if (n < N) u = Xs[(size_t)n * 512 + b * 16 + jj];
        float* sp = &sA[r * 65 + jj * 4];
        sp[0] = bflo(u.x); sp[1] = bfhi(u.x);
        sp[2] = bflo(u.y); sp[3] = bfhi(u.y);
      }
    }
    __syncthreads();

    const float* ap0 = &sA[(np * 2) * 65];
    const float* ap1 = ap0 + 65;
#pragma unroll
    for (int d = 0; d < 64; ++d) {
      float x0 = ap0[d], x1 = ap1[d];
      float4 w0 = sW[d * 16 + og * 2];
      float4 w1 = sW[d * 16 + og * 2 + 1];
      fma4(a00, x0, w0); fma4(a01, x0, w1);
      fma4(a10, x1, w0); fma4(a11, x1, w1);
    }
    __syncthreads();
  }

  int n = n0 + np * 2;
  if (n < N) {
    float4* op = &out4[((size_t)b * N + n) * 16 + og * 2];
    if (ADD) {
      float4 c0 = op[0], c1 = op[1];
      c0.x += a00.x; c0.y += a00.y; c0.z += a00.z; c0.w += a00.w;
      c1.x += a01.x; c1.y += a01.y; c1.z += a01.z; c1.w += a01.w;
      op[0] = c0; op[1] = c1;
    } else {
      op[0] = a00; op[1] = a01;
    }
  }
  if (n + 1 < N) {
    float4* op = &out4[((size_t)b * N + n + 1) * 16 + og * 2];
    if (ADD) {
      float4 c0 = op[0], c1 = op[1];
      c0.x += a10.x; c0.y += a10.y; c0.z += a10.z; c0.w += a10.w;
      c1.x += a11.x; c1.y += a11.y; c1.z += a11.z; c1.w += a11.w;
      op[0] = c0; op[1] = c1;
    } else {
      op[0] = a10; op[1] = a11;
    }
  }
}

// ---------------- launch ----------------

extern "C" void kernel_launch(void* const* d_in, const int* in_sizes, int n_in,
                              void* d_out, int out_size, void* d_ws, size_t ws_size,
                              hipStream_t stream) {
  const float* inp = (const float*)d_in[0];
  const int*   rws[2] = {(const int*)d_in[1], (const int*)d_in[4]};
  const int*   cls[2] = {(const int*)d_in[2], (const int*)d_in[5]};
  const float* vls[2] = {(const float*)d_in[3], (const float*)d_in[6]};
  const float* W    = (const float*)d_in[7];
  const float* bias = (const float*)d_in[8];
  float* out = (float*)d_out;

  const int N = in_sizes[0] / C;          // 20000
  const int Emax = (in_sizes[1] > in_sizes[4]) ? in_sizes[1] : in_sizes[4];

  // workspace layout: X1, X2, edges, ptr/counts, then X0 fp16 tail (guarded)
  char* ws = (char*)d_ws;
  size_t rowBytes = (size_t)C * 2;                        // 4096 B/node (bf16 or fp16)
  ushort* X1 = (ushort*)ws;                size_t off = (size_t)N * rowBytes;  // 81.92 MB
  ushort* X2 = (ushort*)(ws + off);        off += (size_t)N * rowBytes;        // 81.92 MB
  int*   ecol = (int*)(ws + off);          off += (size_t)Emax * 4;
  float* evalv = (float*)(ws + off);       off += (size_t)Emax * 4;
  int*   row_ptr = (int*)(ws + off);       off += (size_t)(N + 1) * 4;
  off = (off + 255) & ~(size_t)255;
  int*   counts = (int*)(ws + off);        off += (size_t)N * 4;
  off = (off + 255) & ~(size_t)255;
  ushort* X0 = (ushort*)(ws + off);        off += (size_t)N * rowBytes;        // 81.92 MB
  const bool useX0 = (ws_size >= off);
  (void)n_in; (void)out_size;

  dim3 gp((N + 63) / 64, B);

  if (useX0) {
    pack_x0<<<N, 256, 0, stream>>>((const float4*)inp, (uint4*)X0, N);
  }

  for (int s = 0; s < 2; ++s) {
    const int E = in_sizes[s == 0 ? 1 : 4];

    hipMemsetAsync(counts, 0, (size_t)N * 4, stream);
    hist_k<<<(E + 255) / 256, 256, 0, stream>>>(rws[s], counts, E);
    scan_k<<<1, 256, 0, stream>>>(counts, row_ptr, N);
    hipMemsetAsync(counts, 0, (size_t)N * 4, stream);
    fill_k<<<(E + 255) / 256, 256, 0, stream>>>(rws[s], cls[s], vls[s], row_ptr,
                                                counts, ecol, evalv, E);

    if (useX0) {
      spmm_g<true><<<N, 256, 0, stream>>>((const uint4*)X0, row_ptr, ecol, evalv,
                                          (uint4*)X1, N);
    } else {
      spmm1<<<N, 256, 0, stream>>>((const float4*)inp, row_ptr, ecol, evalv,
                                   (uint2*)X1, N);
    }
    spmm_g<false><<<N, 256, 0, stream>>>((const uint4*)X1, row_ptr, ecol, evalv,
                                         (uint4*)X2, N);

    if (s == 0) {
      proj_gemm<false><<<gp, 256, 0, stream>>>((const float4*)inp, (const uint2*)X1,
                                               (const uint2*)X2, (const float4*)W, 0,
                                               (const float4*)bias, (float4*)out, N);
    } else {
      proj_gemm<true><<<gp, 256, 0, stream>>>((const float4*)inp, (const uint2*)X1,
                                              (const uint2*)X2, (const float4*)W, 192,
                                              (const float4*)bias, (float4*)out, N);
    }
  }
}

// Round 3
// 2249.756 us; speedup vs baseline: 1.5226x; 1.2492x over previous
//
#include <hip/hip_runtime.h>
#include <hip/hip_fp16.h>

// DiffusionConvolution: out[b,n,o] = bias[o] + sum_{s,k,d} (A_s^k x0)[n,(d,b)] * W[(s*3+k)*64+d, o]
// B=32, N=20000, D=OUT=64, K=2, E=640000 per support.
//
// R6 = R5 resubmit (container infra failure last round; kernel re-audited).
//   wt_prep: W fp32 [384][64] -> Wt bf16 hi/lo, transposed [6 sj][64 o][64 k] (96 KB, L2)
//   pack_x0: inp fp32 [B,N,D] -> X0 fp16 node-major [N, 2048] (82 MB, L3-resident)
//   per support s:
//     CSR build; spmm_g<half>: X1 = A*X0 (fp16 gather); spmm_g<bf16>: X2 = A*X1
//     proj_mfma<ADD=s>: MFMA 16x16x32 bf16 GEMM, out tile 64n x 64o per (block, b).
//       j=0 term: split-bf16 A (inp) x split-bf16 W -> 3 MFMAs/chunk (~fp32 exact)
//       j=1,2:    X bf16 (as stored) x split-bf16 W -> 2 MFMAs/chunk
//       LDS tiles XOR-swizzled (16B-block index ^= row&7) for bank-balanced ds_read_b128.
// Workspace: X1 82 + X2 82 + edges 5.1 + ptr/counts 0.2 + Wt 0.1 + X0 82 = ~252 MB.

constexpr int B = 32;
constexpr int D = 64;
constexpr int C = B * D;   // 2048 features per node

typedef short bf16x8 __attribute__((ext_vector_type(8)));
typedef float f32x4 __attribute__((ext_vector_type(4)));

__device__ __forceinline__ void fma4(float4& a, float s, const float4 b) {
  a.x = fmaf(s, b.x, a.x);
  a.y = fmaf(s, b.y, a.y);
  a.z = fmaf(s, b.z, a.z);
  a.w = fmaf(s, b.w, a.w);
}

__device__ __forceinline__ unsigned f2bf(float f) {
  union { float f; unsigned u; } v; v.f = f;
  return (v.u + 0x7fffu + ((v.u >> 16) & 1u)) >> 16;   // RNE
}
__device__ __forceinline__ unsigned pk(float a, float b) {
  return f2bf(a) | (f2bf(b) << 16);
}
__device__ __forceinline__ float bflo(unsigned u) { return __uint_as_float(u << 16); }
__device__ __forceinline__ float bfhi(unsigned u) { return __uint_as_float(u & 0xffff0000u); }

__device__ __forceinline__ unsigned pkh(float a, float b) {
  union { __half2 h; unsigned u; } c;
  c.h = __floats2half2_rn(a, b);
  return c.u;
}

__device__ __forceinline__ void fma8(float4& a0, float4& a1, float v, uint4 u) {
  a0.x = fmaf(v, bflo(u.x), a0.x); a0.y = fmaf(v, bfhi(u.x), a0.y);
  a0.z = fmaf(v, bflo(u.y), a0.z); a0.w = fmaf(v, bfhi(u.y), a0.w);
  a1.x = fmaf(v, bflo(u.z), a1.x); a1.y = fmaf(v, bfhi(u.z), a1.y);
  a1.z = fmaf(v, bflo(u.w), a1.z); a1.w = fmaf(v, bfhi(u.w), a1.w);
}

__device__ __forceinline__ void fma8h(float4& a0, float4& a1, float v, uint4 u) {
  union { unsigned u; __half2 h; } c0, c1, c2, c3;
  c0.u = u.x; c1.u = u.y; c2.u = u.z; c3.u = u.w;
  float2 f0 = __half22float2(c0.h);
  float2 f1 = __half22float2(c1.h);
  float2 f2 = __half22float2(c2.h);
  float2 f3 = __half22float2(c3.h);
  a0.x = fmaf(v, f0.x, a0.x); a0.y = fmaf(v, f0.y, a0.y);
  a0.z = fmaf(v, f1.x, a0.z); a0.w = fmaf(v, f1.y, a0.w);
  a1.x = fmaf(v, f2.x, a1.x); a1.y = fmaf(v, f2.y, a1.y);
  a1.z = fmaf(v, f3.x, a1.z); a1.w = fmaf(v, f3.y, a1.w);
}

// ---------------- CSR build ----------------

__global__ __launch_bounds__(256) void hist_k(const int* __restrict__ rows,
                                              int* __restrict__ counts, int E) {
  int e = blockIdx.x * 256 + threadIdx.x;
  if (e < E) atomicAdd(&counts[rows[e]], 1);
}

__global__ __launch_bounds__(256) void scan_k(const int* __restrict__ counts,
                                              int* __restrict__ row_ptr, int N) {
  __shared__ int part[256];
  int t = threadIdx.x;
  int chunk = (N + 255) >> 8;
  int lo = t * chunk; if (lo > N) lo = N;
  int hi = lo + chunk; if (hi > N) hi = N;
  int s = 0;
  for (int i = lo; i < hi; ++i) s += counts[i];
  part[t] = s;
  __syncthreads();
  for (int off = 1; off < 256; off <<= 1) {
    int x = (t >= off) ? part[t - off] : 0;
    __syncthreads();
    part[t] += x;
    __syncthreads();
  }
  int run = part[t] - s;
  for (int i = lo; i < hi; ++i) { row_ptr[i] = run; run += counts[i]; }
  if (t == 255) row_ptr[N] = part[255];
}

__global__ __launch_bounds__(256) void fill_k(const int* __restrict__ rows,
                                              const int* __restrict__ cols,
                                              const float* __restrict__ vals,
                                              const int* __restrict__ row_ptr,
                                              int* __restrict__ cursor,
                                              int* __restrict__ ecol,
                                              float* __restrict__ eval, int E) {
  int e = blockIdx.x * 256 + threadIdx.x;
  if (e < E) {
    int r = rows[e];
    int pos = row_ptr[r] + atomicAdd(&cursor[r], 1);
    ecol[pos] = cols[e];
    eval[pos] = vals[e];
  }
}

// ---------------- wt_prep: W fp32 [384][64] -> Wt hi/lo bf16 [6][64 o][64 k] ----------------

__global__ __launch_bounds__(256) void wt_prep(const float* __restrict__ W,
                                               ushort* __restrict__ Whi,
                                               ushort* __restrict__ Wlo) {
  int idx = blockIdx.x * 256 + threadIdx.x;
  if (idx >= 384 * 64) return;
  int g = idx >> 6, o = idx & 63;            // g = s*192 + j*64 + k
  int s = g / 192, rem = g - s * 192;
  int j = rem >> 6, k = rem & 63;
  float v = W[g * 64 + o];
  unsigned hb = f2bf(v);
  float hf = __uint_as_float(hb << 16);
  unsigned lb = f2bf(v - hf);
  int pos = ((s * 3 + j) * 64 + o) * 64 + k;
  Whi[pos] = (ushort)hb;
  Wlo[pos] = (ushort)lb;
}

// ---------------- pack_x0: inp fp32 [B,N,D] -> X0 fp16 node-major [N, 2048] ----------------

__global__ __launch_bounds__(256) void pack_x0(const float4* __restrict__ inp4,
                                               uint4* __restrict__ X0u4, int N) {
  int n = blockIdx.x, t = threadIdx.x;
  int b = t >> 3, j = t & 7;
  const float4* p = inp4 + ((size_t)b * N + n) * 16 + j * 2;
  float4 v0 = p[0], v1 = p[1];
  X0u4[(size_t)n * 256 + t] = make_uint4(pkh(v0.x, v0.y), pkh(v0.z, v0.w),
                                         pkh(v1.x, v1.y), pkh(v1.z, v1.w));
}

// ---------------- spmm_g: D = A * S, 16-bit gather (fp16 or bf16), bf16 write ----------------

template <bool HALF>
__global__ __launch_bounds__(256) void spmm_g(const uint4* __restrict__ Su4,
                                              const int* __restrict__ row_ptr,
                                              const int* __restrict__ ecol,
                                              const float* __restrict__ eval,
                                              uint4* __restrict__ Du4, int N) {
  int t = threadIdx.x;
  int n = blockIdx.x;
  float4 acc0 = {0.f, 0.f, 0.f, 0.f};
  float4 acc1 = {0.f, 0.f, 0.f, 0.f};
  int start = row_ptr[n], end = row_ptr[n + 1];
  const uint4* sp = Su4 + t;
  int e = start;
  for (; e + 4 <= end; e += 4) {
    int c0 = ecol[e], c1 = ecol[e + 1], c2 = ecol[e + 2], c3 = ecol[e + 3];
    float v0 = eval[e], v1 = eval[e + 1], v2 = eval[e + 2], v3 = eval[e + 3];
    uint4 u0 = sp[(size_t)c0 * 256];
    uint4 u1 = sp[(size_t)c1 * 256];
    uint4 u2 = sp[(size_t)c2 * 256];
    uint4 u3 = sp[(size_t)c3 * 256];
    if (HALF) {
      fma8h(acc0, acc1, v0, u0); fma8h(acc0, acc1, v1, u1);
      fma8h(acc0, acc1, v2, u2); fma8h(acc0, acc1, v3, u3);
    } else {
      fma8(acc0, acc1, v0, u0); fma8(acc0, acc1, v1, u1);
      fma8(acc0, acc1, v2, u2); fma8(acc0, acc1, v3, u3);
    }
  }
  for (; e < end; ++e) {
    uint4 u = sp[(size_t)ecol[e] * 256];
    if (HALF) fma8h(acc0, acc1, eval[e], u);
    else      fma8(acc0, acc1, eval[e], u);
  }
  Du4[(size_t)n * 256 + t] = make_uint4(pk(acc0.x, acc0.y), pk(acc0.z, acc0.w),
                                        pk(acc1.x, acc1.y), pk(acc1.z, acc1.w));
}

// ---------------- spmm1 (fallback, no-X0 path): fp32 gather from inp ----------------

__global__ __launch_bounds__(256) void spmm1(const float4* __restrict__ inp4,
                                             const int* __restrict__ row_ptr,
                                             const int* __restrict__ ecol,
                                             const float* __restrict__ eval,
                                             uint2* __restrict__ X1u2, int N) {
  int t = threadIdx.x;
  int n = blockIdx.x;
  float4 acc0 = {0.f, 0.f, 0.f, 0.f};
  float4 acc1 = {0.f, 0.f, 0.f, 0.f};
  int start = row_ptr[n], end = row_ptr[n + 1];
  const float4* p0 = inp4 + (size_t)(t >> 4) * (N * 16) + (t & 15);
  const float4* p1 = inp4 + (size_t)((t >> 4) + 16) * (N * 16) + (t & 15);
  for (int e = start; e < end; ++e) {
    int col = ecol[e];
    float v = eval[e];
    fma4(acc0, v, p0[(size_t)col * 16]);
    fma4(acc1, v, p1[(size_t)col * 16]);
  }
  size_t idx = (size_t)n * 512 + (t >> 4) * 16 + (t & 15);
  X1u2[idx]       = make_uint2(pk(acc0.x, acc0.y), pk(acc0.z, acc0.w));
  X1u2[idx + 256] = make_uint2(pk(acc1.x, acc1.y), pk(acc1.z, acc1.w));
}

// ---------------- proj_mfma: out (+)= inp*W0 + X1*W1 + X2*W2 (+bias) via MFMA ----------------
// grid ((N+63)/64, B), 256 threads = 4 waves. Out tile 64n x 64o for batch b.
// Wave w owns rows [16w,16w+16) x 64 cols = 4 subtiles of 16x16; acc = 4 x f32x4.
// mfma_f32_16x16x32_bf16 layouts (m89-verified):
//   A frag: lane l holds A[l&15, 8*(l>>4)+e], e=0..7 (16B contiguous in k)
//   B frag: lane l holds B[8*(l>>4)+e, l&15]  -> stage W transposed [o][k]
//   C/D:    col = l&15, row = (l>>4)*4 + reg
// LDS tiles [64 rows][64 k] bf16, 128 B/row; 16B-block index ^= (row&7).
// Swizzle is write/read-consistent: every staged write (8B/16B) sits inside one 16B block.

template <bool ADD>
__global__ __launch_bounds__(256) void proj_mfma(const float4* __restrict__ inp4,
                                                 const uint4* __restrict__ X1u4,
                                                 const uint4* __restrict__ X2u4,
                                                 const ushort* __restrict__ Whi,
                                                 const ushort* __restrict__ Wlo,
                                                 int sj0,   // 3*s
                                                 const float* __restrict__ bias,
                                                 float* __restrict__ out, int N) {
  __shared__ uint4 ldsbuf[2048];       // 32 KB
  char* sAhi = (char*)ldsbuf;          // 8 KB  [64 n][64 k] bf16
  char* sAlo = sAhi + 8192;            // 8 KB  (j==0 only)
  char* sWhi = sAhi + 16384;           // 8 KB  [64 o][64 k] bf16
  char* sWlo = sAhi + 24576;           // 8 KB

  int t = threadIdx.x;
  int lane = t & 63, w = t >> 6;
  int b = blockIdx.y;
  int n0 = blockIdx.x * 64;
  int col = lane & 15, kg = lane >> 4;

  f32x4 acc[4];
  if (ADD) {
#pragma unroll
    for (int c = 0; c < 4; ++c) acc[c] = (f32x4){0.f, 0.f, 0.f, 0.f};
  } else {
#pragma unroll
    for (int c = 0; c < 4; ++c) {
      float bv = bias[c * 16 + col];
      acc[c] = (f32x4){bv, bv, bv, bv};
    }
  }

  for (int j = 0; j < 3; ++j) {
    // ---- stage W hi/lo (transposed layout [o][k], swizzled) ----
    {
      const uint4* srcH = (const uint4*)(Whi + (size_t)(sj0 + j) * 4096);
      const uint4* srcL = (const uint4*)(Wlo + (size_t)(sj0 + j) * 4096);
#pragma unroll
      for (int kk = 0; kk < 2; ++kk) {
        int q = t + 256 * kk;
        int o = q >> 3, x8 = q & 7;
        int doff = o * 128 + ((x8 * 16) ^ ((o & 7) << 4));
        *(uint4*)(sWhi + doff) = srcH[q];
        *(uint4*)(sWlo + doff) = srcL[q];
      }
    }
    // ---- stage A tile ----
    if (j == 0) {
      // inp fp32 -> split bf16 hi+lo
#pragma unroll
      for (int kk = 0; kk < 4; ++kk) {
        int q = t + 256 * kk;
        int r = q >> 4, d4 = q & 15;
        int n = n0 + r;
        float4 v = {0.f, 0.f, 0.f, 0.f};
        if (n < N) v = inp4[((size_t)b * N + n) * 16 + d4];
        unsigned h0 = pk(v.x, v.y), h1 = pk(v.z, v.w);
        float lx = v.x - bflo(h0), ly = v.y - bfhi(h0);
        float lz = v.z - bflo(h1), lw = v.w - bfhi(h1);
        int doff = r * 128 + ((d4 * 8) ^ ((r & 7) << 4));
        *(uint2*)(sAhi + doff) = make_uint2(h0, h1);
        *(uint2*)(sAlo + doff) = make_uint2(pk(lx, ly), pk(lz, lw));
      }
    } else {
      const uint4* Xs = (j == 1) ? X1u4 : X2u4;
#pragma unroll
      for (int kk = 0; kk < 2; ++kk) {
        int q = t + 256 * kk;
        int r = q >> 3, x8 = q & 7;
        int n = n0 + r;
        uint4 u = {0u, 0u, 0u, 0u};
        if (n < N) u = Xs[(size_t)n * 256 + b * 8 + x8];
        int doff = r * 128 + ((x8 * 16) ^ ((r & 7) << 4));
        *(uint4*)(sAhi + doff) = u;
      }
    }
    __syncthreads();

    // ---- MFMA: K=64 in 2 chunks of 32 ----
#pragma unroll
    for (int kc = 0; kc < 2; ++kc) {
      int kb = kc * 64 + kg * 16;                 // byte offset of this lane's 8 k's
      int arow = w * 16 + col;
      int aoff = arow * 128 + (kb ^ ((arow & 7) << 4));
      bf16x8 ah = *(const bf16x8*)(sAhi + aoff);
      bf16x8 al;
      if (j == 0) al = *(const bf16x8*)(sAlo + aoff);
#pragma unroll
      for (int c = 0; c < 4; ++c) {
        int wrow = c * 16 + col;
        int woff = wrow * 128 + (kb ^ ((wrow & 7) << 4));
        bf16x8 bh = *(const bf16x8*)(sWhi + woff);
        bf16x8 bl = *(const bf16x8*)(sWlo + woff);
        acc[c] = __builtin_amdgcn_mfma_f32_16x16x32_bf16(ah, bh, acc[c], 0, 0, 0);
        acc[c] = __builtin_amdgcn_mfma_f32_16x16x32_bf16(ah, bl, acc[c], 0, 0, 0);
        if (j == 0)
          acc[c] = __builtin_amdgcn_mfma_f32_16x16x32_bf16(al, bh, acc[c], 0, 0, 0);
      }
    }
    __syncthreads();
  }

  // ---- store: row = n0 + 16w + 4*kg + reg, col = 16c + (lane&15) ----
  int rbase = n0 + w * 16 + kg * 4;
  size_t obase = (size_t)b * N * 64;
#pragma unroll
  for (int c = 0; c < 4; ++c) {
#pragma unroll
    for (int r = 0; r < 4; ++r) {
      int row = rbase + r;
      if (row < N) {
        float* op = out + obase + (size_t)row * 64 + c * 16 + col;
        float vv = acc[c][r];
        if (ADD) *op += vv; else *op = vv;
      }
    }
  }
}

// ---------------- launch ----------------

extern "C" void kernel_launch(void* const* d_in, const int* in_sizes, int n_in,
                              void* d_out, int out_size, void* d_ws, size_t ws_size,
                              hipStream_t stream) {
  const float* inp = (const float*)d_in[0];
  const int*   rws[2] = {(const int*)d_in[1], (const int*)d_in[4]};
  const int*   cls[2] = {(const int*)d_in[2], (const int*)d_in[5]};
  const float* vls[2] = {(const float*)d_in[3], (const float*)d_in[6]};
  const float* W    = (const float*)d_in[7];
  const float* bias = (const float*)d_in[8];
  float* out = (float*)d_out;

  const int N = in_sizes[0] / C;          // 20000
  const int Emax = (in_sizes[1] > in_sizes[4]) ? in_sizes[1] : in_sizes[4];

  // workspace layout: X1, X2, edges, ptr/counts, Wt hi/lo, then X0 fp16 tail (guarded)
  char* ws = (char*)d_ws;
  size_t rowBytes = (size_t)C * 2;                        // 4096 B/node (bf16 or fp16)
  ushort* X1 = (ushort*)ws;                size_t off = (size_t)N * rowBytes;  // 81.92 MB
  ushort* X2 = (ushort*)(ws + off);        off += (size_t)N * rowBytes;        // 81.92 MB
  int*   ecol = (int*)(ws + off);          off += (size_t)Emax * 4;
  float* evalv = (float*)(ws + off);       off += (size_t)Emax * 4;
  int*   row_ptr = (int*)(ws + off);       off += (size_t)(N + 1) * 4;
  off = (off + 255) & ~(size_t)255;
  int*   counts = (int*)(ws + off);        off += (size_t)N * 4;
  off = (off + 255) & ~(size_t)255;
  ushort* Wt_hi = (ushort*)(ws + off);     off += (size_t)6 * 64 * 64 * 2;     // 48 KB
  ushort* Wt_lo = (ushort*)(ws + off);     off += (size_t)6 * 64 * 64 * 2;     // 48 KB
  off = (off + 255) & ~(size_t)255;
  ushort* X0 = (ushort*)(ws + off);        off += (size_t)N * rowBytes;        // 81.92 MB
  const bool useX0 = (ws_size >= off);
  (void)n_in; (void)out_size;

  dim3 gp((N + 63) / 64, B);

  wt_prep<<<96, 256, 0, stream>>>(W, Wt_hi, Wt_lo);
  if (useX0) {
    pack_x0<<<N, 256, 0, stream>>>((const float4*)inp, (uint4*)X0, N);
  }

  for (int s = 0; s < 2; ++s) {
    const int E = in_sizes[s == 0 ? 1 : 4];

    hipMemsetAsync(counts, 0, (size_t)N * 4, stream);
    hist_k<<<(E + 255) / 256, 256, 0, stream>>>(rws[s], counts, E);
    scan_k<<<1, 256, 0, stream>>>(counts, row_ptr, N);
    hipMemsetAsync(counts, 0, (size_t)N * 4, stream);
    fill_k<<<(E + 255) / 256, 256, 0, stream>>>(rws[s], cls[s], vls[s], row_ptr,
                                                counts, ecol, evalv, E);

    if (useX0) {
      spmm_g<true><<<N, 256, 0, stream>>>((const uint4*)X0, row_ptr, ecol, evalv,
                                          (uint4*)X1, N);
    } else {
      spmm1<<<N, 256, 0, stream>>>((const float4*)inp, row_ptr, ecol, evalv,
                                   (uint2*)X1, N);
    }
    spmm_g<false><<<N, 256, 0, stream>>>((const uint4*)X1, row_ptr, ecol, evalv,
                                         (uint4*)X2, N);

    if (s == 0) {
      proj_mfma<false><<<gp, 256, 0, stream>>>((const float4*)inp, (const uint4*)X1,
                                               (const uint4*)X2, Wt_hi, Wt_lo, 0,
                                               bias, out, N);
    } else {
      proj_mfma<true><<<gp, 256, 0, stream>>>((const float4*)inp, (const uint4*)X1,
                                              (const uint4*)X2, Wt_hi, Wt_lo, 3,
                                              bias, out, N);
    }
  }
}

// Round 4
// 2057.583 us; speedup vs baseline: 1.6649x; 1.0934x over previous
//
#include <hip/hip_runtime.h>
#include <hip/hip_fp16.h>

// DiffusionConvolution: out[b,n,o] = bias[o] + sum_{s,k,d} (A_s^k x0)[n,(d,b)] * W[(s*3+k)*64+d, o]
// B=32, N=20000, D=OUT=64, K=2, E=640000 per support.
//
// R7 structure (chunked SpMM, L2-resident slabs):
//   X0/X1/X2 in BLOCKED layout X[b][n][64 feats] — per-b slab = N*128 B = 2.56 MB < 4 MB L2.
//   pack_x0: pure streaming convert inp fp32 [b][n][d] -> X0 fp16 [b][n][d] (82 MB).
//   per support s:
//     CSR build (euv = packed (col,val) uint2)
//     spmm_c<half>: X1 = A*X0, chunk-per-XCD-pinned gather (1-D grid: xcd=i&7,
//       c = xcd + 8*(j/RG), rg = j%RG). Wave per row: 8 lanes/edge x 8 edge slots,
//       butterfly shfl_xor(8,16,32) reduce, slot-0 lanes write 16 B bf16.
//     spmm_c<bf16>: X2 = A*X1 (same kernel)
//     proj_mfma<ADD=s>: MFMA 16x16x32 bf16 GEMM (split-bf16 W; j=0 split-bf16 A from fp32 inp)
// Workspace: X1 82 + X2 82 + euv 5.1 + ptr/counts 0.2 + Wt 0.2 + X0 82 = ~252 MB.

constexpr int B = 32;
constexpr int D = 64;
constexpr int C = B * D;   // 2048 features per node

typedef short bf16x8 __attribute__((ext_vector_type(8)));
typedef float f32x4 __attribute__((ext_vector_type(4)));

__device__ __forceinline__ void fma4(float4& a, float s, const float4 b) {
  a.x = fmaf(s, b.x, a.x);
  a.y = fmaf(s, b.y, a.y);
  a.z = fmaf(s, b.z, a.z);
  a.w = fmaf(s, b.w, a.w);
}

__device__ __forceinline__ unsigned f2bf(float f) {
  union { float f; unsigned u; } v; v.f = f;
  return (v.u + 0x7fffu + ((v.u >> 16) & 1u)) >> 16;   // RNE
}
__device__ __forceinline__ unsigned pk(float a, float b) {
  return f2bf(a) | (f2bf(b) << 16);
}
__device__ __forceinline__ float bflo(unsigned u) { return __uint_as_float(u << 16); }
__device__ __forceinline__ float bfhi(unsigned u) { return __uint_as_float(u & 0xffff0000u); }

__device__ __forceinline__ unsigned pkh(float a, float b) {
  union { __half2 h; unsigned u; } c;
  c.h = __floats2half2_rn(a, b);
  return c.u;
}

__device__ __forceinline__ void fma8(float4& a0, float4& a1, float v, uint4 u) {
  a0.x = fmaf(v, bflo(u.x), a0.x); a0.y = fmaf(v, bfhi(u.x), a0.y);
  a0.z = fmaf(v, bflo(u.y), a0.z); a0.w = fmaf(v, bfhi(u.y), a0.w);
  a1.x = fmaf(v, bflo(u.z), a1.x); a1.y = fmaf(v, bfhi(u.z), a1.y);
  a1.z = fmaf(v, bflo(u.w), a1.z); a1.w = fmaf(v, bfhi(u.w), a1.w);
}

__device__ __forceinline__ void fma8h(float4& a0, float4& a1, float v, uint4 u) {
  union { unsigned u; __half2 h; } c0, c1, c2, c3;
  c0.u = u.x; c1.u = u.y; c2.u = u.z; c3.u = u.w;
  float2 f0 = __half22float2(c0.h);
  float2 f1 = __half22float2(c1.h);
  float2 f2 = __half22float2(c2.h);
  float2 f3 = __half22float2(c3.h);
  a0.x = fmaf(v, f0.x, a0.x); a0.y = fmaf(v, f0.y, a0.y);
  a0.z = fmaf(v, f1.x, a0.z); a0.w = fmaf(v, f1.y, a0.w);
  a1.x = fmaf(v, f2.x, a1.x); a1.y = fmaf(v, f2.y, a1.y);
  a1.z = fmaf(v, f3.x, a1.z); a1.w = fmaf(v, f3.y, a1.w);
}

// ---------------- CSR build ----------------

__global__ __launch_bounds__(256) void hist_k(const int* __restrict__ rows,
                                              int* __restrict__ counts, int E) {
  int e = blockIdx.x * 256 + threadIdx.x;
  if (e < E) atomicAdd(&counts[rows[e]], 1);
}

__global__ __launch_bounds__(256) void scan_k(const int* __restrict__ counts,
                                              int* __restrict__ row_ptr, int N) {
  __shared__ int part[256];
  int t = threadIdx.x;
  int chunk = (N + 255) >> 8;
  int lo = t * chunk; if (lo > N) lo = N;
  int hi = lo + chunk; if (hi > N) hi = N;
  int s = 0;
  for (int i = lo; i < hi; ++i) s += counts[i];
  part[t] = s;
  __syncthreads();
  for (int off = 1; off < 256; off <<= 1) {
    int x = (t >= off) ? part[t - off] : 0;
    __syncthreads();
    part[t] += x;
    __syncthreads();
  }
  int run = part[t] - s;
  for (int i = lo; i < hi; ++i) { row_ptr[i] = run; run += counts[i]; }
  if (t == 255) row_ptr[N] = part[255];
}

__global__ __launch_bounds__(256) void fill_k(const int* __restrict__ rows,
                                              const int* __restrict__ cols,
                                              const float* __restrict__ vals,
                                              const int* __restrict__ row_ptr,
                                              int* __restrict__ cursor,
                                              uint2* __restrict__ euv, int E) {
  int e = blockIdx.x * 256 + threadIdx.x;
  if (e < E) {
    int r = rows[e];
    int pos = row_ptr[r] + atomicAdd(&cursor[r], 1);
    euv[pos] = make_uint2((unsigned)cols[e], __float_as_uint(vals[e]));
  }
}

// ---------------- wt_prep: W fp32 [384][64] -> Wt hi/lo bf16 [6][64 o][64 k] ----------------

__global__ __launch_bounds__(256) void wt_prep(const float* __restrict__ W,
                                               ushort* __restrict__ Whi,
                                               ushort* __restrict__ Wlo) {
  int idx = blockIdx.x * 256 + threadIdx.x;
  if (idx >= 384 * 64) return;
  int g = idx >> 6, o = idx & 63;            // g = s*192 + j*64 + k
  int s = g / 192, rem = g - s * 192;
  int j = rem >> 6, k = rem & 63;
  float v = W[g * 64 + o];
  unsigned hb = f2bf(v);
  float hf = __uint_as_float(hb << 16);
  unsigned lb = f2bf(v - hf);
  int pos = ((s * 3 + j) * 64 + o) * 64 + k;
  Whi[pos] = (ushort)hb;
  Wlo[pos] = (ushort)lb;
}

// ---------------- pack_x0: streaming fp32 -> fp16, identical [b][n][d] index ----------------

__global__ __launch_bounds__(256) void pack_x0(const float4* __restrict__ inp4,
                                               uint4* __restrict__ X0u4, long total) {
  long i = (long)blockIdx.x * 256 + threadIdx.x;
  long stride = (long)gridDim.x * 256;
  for (; i < total; i += stride) {
    float4 v0 = inp4[i * 2];
    float4 v1 = inp4[i * 2 + 1];
    X0u4[i] = make_uint4(pkh(v0.x, v0.y), pkh(v0.z, v0.w),
                         pkh(v1.x, v1.y), pkh(v1.z, v1.w));
  }
}

// ---------------- spmm_c: D = A * S, chunked (chunk = batch b, 128 B/row) ----------------
// Blocked layout S[b][n][64 feats] 16-bit. 1-D grid, 32*RG blocks, RG=ceil(N/4).
// Decode: xcd = i&7; j = i>>3; c = xcd + 8*(j/RG); rg = j%RG  -> chunk c pinned to one
// XCD, which sweeps its 4 chunks serially; slab (2.56 MB) stays L2-resident.
// Wave per row (4 waves/block): lane = slot*8 + q; slot = edge slot (8 concurrent edges),
// q = uint4 index within the 128 B chunk row. Butterfly shfl_xor(8,16,32) sums slots.

template <bool HALF>
__global__ __launch_bounds__(256) void spmm_c(const uint4* __restrict__ Su4,
                                              const int* __restrict__ row_ptr,
                                              const uint2* __restrict__ euv,
                                              uint4* __restrict__ Du4,
                                              int N, int RG) {
  int i = blockIdx.x;
  int x = i & 7, j = i >> 3;
  int cg = j / RG, rg = j - cg * RG;
  int c = x + 8 * cg;                      // chunk == batch index b, 0..31
  int t = threadIdx.x;
  int n = rg * 4 + (t >> 6);
  if (n >= N) return;
  int lane = t & 63;
  int slot = lane >> 3, q = lane & 7;

  int start = row_ptr[n], end = row_ptr[n + 1];
  const uint4* src = Su4 + (size_t)c * N * 8 + q;
  float4 a0 = {0.f, 0.f, 0.f, 0.f};
  float4 a1 = {0.f, 0.f, 0.f, 0.f};

  for (int e0 = start; e0 < end; e0 += 8) {
    int e = e0 + slot;
    if (e < end) {
      uint2 ev = euv[e];
      float v = __uint_as_float(ev.y);
      uint4 u = src[(size_t)ev.x * 8];
      if (HALF) fma8h(a0, a1, v, u);
      else      fma8(a0, a1, v, u);
    }
  }

  // reduce over 8 edge slots (lane bits 3,4,5)
#pragma unroll
  for (int m = 8; m <= 32; m <<= 1) {
    a0.x += __shfl_xor(a0.x, m); a0.y += __shfl_xor(a0.y, m);
    a0.z += __shfl_xor(a0.z, m); a0.w += __shfl_xor(a0.w, m);
    a1.x += __shfl_xor(a1.x, m); a1.y += __shfl_xor(a1.y, m);
    a1.z += __shfl_xor(a1.z, m); a1.w += __shfl_xor(a1.w, m);
  }

  if (slot == 0) {
    Du4[((size_t)c * N + n) * 8 + q] = make_uint4(pk(a0.x, a0.y), pk(a0.z, a0.w),
                                                  pk(a1.x, a1.y), pk(a1.z, a1.w));
  }
}

// ---------------- spmm1 (fallback, no-X0 path): fp32 full-row gather, blocked write ----------

__global__ __launch_bounds__(256) void spmm1(const float4* __restrict__ inp4,
                                             const int* __restrict__ row_ptr,
                                             const uint2* __restrict__ euv,
                                             uint2* __restrict__ X1u2, int N) {
  int t = threadIdx.x;
  int n = blockIdx.x;
  float4 acc0 = {0.f, 0.f, 0.f, 0.f};
  float4 acc1 = {0.f, 0.f, 0.f, 0.f};
  int start = row_ptr[n], end = row_ptr[n + 1];
  int b0 = t >> 4;
  const float4* p0 = inp4 + (size_t)b0 * (N * 16) + (t & 15);
  const float4* p1 = inp4 + (size_t)(b0 + 16) * (N * 16) + (t & 15);
  for (int e = start; e < end; ++e) {
    uint2 ev = euv[e];
    float v = __uint_as_float(ev.y);
    fma4(acc0, v, p0[(size_t)ev.x * 16]);
    fma4(acc1, v, p1[(size_t)ev.x * 16]);
  }
  X1u2[((size_t)b0 * N + n) * 16 + (t & 15)] =
      make_uint2(pk(acc0.x, acc0.y), pk(acc0.z, acc0.w));
  X1u2[((size_t)(b0 + 16) * N + n) * 16 + (t & 15)] =
      make_uint2(pk(acc1.x, acc1.y), pk(acc1.z, acc1.w));
}

// ---------------- proj_mfma: out (+)= inp*W0 + X1*W1 + X2*W2 (+bias) via MFMA ----------------
// grid ((N+63)/64, B), 256 threads = 4 waves. Out tile 64n x 64o for batch b.
// X1/X2 now blocked [b][n][64]: tile staging reads 8 KB contiguous.
// mfma_f32_16x16x32_bf16 layouts (m89-verified). LDS 16B-block index ^= (row&7).

template <bool ADD>
__global__ __launch_bounds__(256) void proj_mfma(const float4* __restrict__ inp4,
                                                 const uint4* __restrict__ X1u4,
                                                 const uint4* __restrict__ X2u4,
                                                 const ushort* __restrict__ Whi,
                                                 const ushort* __restrict__ Wlo,
                                                 int sj0,   // 3*s
                                                 const float* __restrict__ bias,
                                                 float* __restrict__ out, int N) {
  __shared__ uint4 ldsbuf[2048];       // 32 KB
  char* sAhi = (char*)ldsbuf;          // 8 KB  [64 n][64 k] bf16
  char* sAlo = sAhi + 8192;            // 8 KB  (j==0 only)
  char* sWhi = sAhi + 16384;           // 8 KB  [64 o][64 k] bf16
  char* sWlo = sAhi + 24576;           // 8 KB

  int t = threadIdx.x;
  int lane = t & 63, w = t >> 6;
  int b = blockIdx.y;
  int n0 = blockIdx.x * 64;
  int col = lane & 15, kg = lane >> 4;

  f32x4 acc[4];
  if (ADD) {
#pragma unroll
    for (int c = 0; c < 4; ++c) acc[c] = (f32x4){0.f, 0.f, 0.f, 0.f};
  } else {
#pragma unroll
    for (int c = 0; c < 4; ++c) {
      float bv = bias[c * 16 + col];
      acc[c] = (f32x4){bv, bv, bv, bv};
    }
  }

  for (int j = 0; j < 3; ++j) {
    // ---- stage W slice hi/lo (transposed [o][k], swizzled) ----
    {
      const uint4* srcH = (const uint4*)(Whi + (size_t)(sj0 + j) * 4096);
      const uint4* srcL = (const uint4*)(Wlo + (size_t)(sj0 + j) * 4096);
#pragma unroll
      for (int kk = 0; kk < 2; ++kk) {
        int q = t + 256 * kk;
        int o = q >> 3, x8 = q & 7;
        int doff = o * 128 + ((x8 * 16) ^ ((o & 7) << 4));
        *(uint4*)(sWhi + doff) = srcH[q];
        *(uint4*)(sWlo + doff) = srcL[q];
      }
    }
    // ---- stage A tile ----
    if (j == 0) {
      // inp fp32 -> split bf16 hi+lo
#pragma unroll
      for (int kk = 0; kk < 4; ++kk) {
        int q = t + 256 * kk;
        int r = q >> 4, d4 = q & 15;
        int n = n0 + r;
        float4 v = {0.f, 0.f, 0.f, 0.f};
        if (n < N) v = inp4[((size_t)b * N + n) * 16 + d4];
        unsigned h0 = pk(v.x, v.y), h1 = pk(v.z, v.w);
        float lx = v.x - bflo(h0), ly = v.y - bfhi(h0);
        float lz = v.z - bflo(h1), lw = v.w - bfhi(h1);
        int doff = r * 128 + ((d4 * 8) ^ ((r & 7) << 4));
        *(uint2*)(sAhi + doff) = make_uint2(h0, h1);
        *(uint2*)(sAlo + doff) = make_uint2(pk(lx, ly), pk(lz, lw));
      }
    } else {
      const uint4* Xs = (j == 1) ? X1u4 : X2u4;
#pragma unroll
      for (int kk = 0; kk < 2; ++kk) {
        int q = t + 256 * kk;
        int r = q >> 3, x8 = q & 7;
        int n = n0 + r;
        uint4 u = {0u, 0u, 0u, 0u};
        if (n < N) u = Xs[((size_t)b * N + n) * 8 + x8];
        int doff = r * 128 + ((x8 * 16) ^ ((r & 7) << 4));
        *(uint4*)(sAhi + doff) = u;
      }
    }
    __syncthreads();

    // ---- MFMA: K=64 in 2 chunks of 32 ----
#pragma unroll
    for (int kc = 0; kc < 2; ++kc) {
      int kb = kc * 64 + kg * 16;                 // byte offset of this lane's 8 k's
      int arow = w * 16 + col;
      int aoff = arow * 128 + (kb ^ ((arow & 7) << 4));
      bf16x8 ah = *(const bf16x8*)(sAhi + aoff);
      bf16x8 al;
      if (j == 0) al = *(const bf16x8*)(sAlo + aoff);
#pragma unroll
      for (int c = 0; c < 4; ++c) {
        int wrow = c * 16 + col;
        int woff = wrow * 128 + (kb ^ ((wrow & 7) << 4));
        bf16x8 bh = *(const bf16x8*)(sWhi + woff);
        bf16x8 bl = *(const bf16x8*)(sWlo + woff);
        acc[c] = __builtin_amdgcn_mfma_f32_16x16x32_bf16(ah, bh, acc[c], 0, 0, 0);
        acc[c] = __builtin_amdgcn_mfma_f32_16x16x32_bf16(ah, bl, acc[c], 0, 0, 0);
        if (j == 0)
          acc[c] = __builtin_amdgcn_mfma_f32_16x16x32_bf16(al, bh, acc[c], 0, 0, 0);
      }
    }
    __syncthreads();
  }

  // ---- store: row = n0 + 16w + 4*kg + reg, col = 16c + (lane&15) ----
  int rbase = n0 + w * 16 + kg * 4;
  size_t obase = (size_t)b * N * 64;
#pragma unroll
  for (int c = 0; c < 4; ++c) {
#pragma unroll
    for (int r = 0; r < 4; ++r) {
      int row = rbase + r;
      if (row < N) {
        float* op = out + obase + (size_t)row * 64 + c * 16 + col;
        float vv = acc[c][r];
        if (ADD) *op += vv; else *op = vv;
      }
    }
  }
}

// ---------------- launch ----------------

extern "C" void kernel_launch(void* const* d_in, const int* in_sizes, int n_in,
                              void* d_out, int out_size, void* d_ws, size_t ws_size,
                              hipStream_t stream) {
  const float* inp = (const float*)d_in[0];
  const int*   rws[2] = {(const int*)d_in[1], (const int*)d_in[4]};
  const int*   cls[2] = {(const int*)d_in[2], (const int*)d_in[5]};
  const float* vls[2] = {(const float*)d_in[3], (const float*)d_in[6]};
  const float* W    = (const float*)d_in[7];
  const float* bias = (const float*)d_in[8];
  float* out = (float*)d_out;

  const int N = in_sizes[0] / C;          // 20000
  const int Emax = (in_sizes[1] > in_sizes[4]) ? in_sizes[1] : in_sizes[4];

  // workspace layout: X1, X2, euv, ptr/counts, Wt hi/lo, then X0 fp16 tail (guarded)
  char* ws = (char*)d_ws;
  size_t rowBytes = (size_t)C * 2;                        // 4096 B/node (bf16 or fp16)
  ushort* X1 = (ushort*)ws;                size_t off = (size_t)N * rowBytes;  // 81.92 MB
  ushort* X2 = (ushort*)(ws + off);        off += (size_t)N * rowBytes;        // 81.92 MB
  uint2* euv = (uint2*)(ws + off);         off += (size_t)Emax * 8;
  int*   row_ptr = (int*)(ws + off);       off += (size_t)(N + 1) * 4;
  off = (off + 255) & ~(size_t)255;
  int*   counts = (int*)(ws + off);        off += (size_t)N * 4;
  off = (off + 255) & ~(size_t)255;
  ushort* Wt_hi = (ushort*)(ws + off);     off += (size_t)6 * 64 * 64 * 2;     // 48 KB
  ushort* Wt_lo = (ushort*)(ws + off);     off += (size_t)6 * 64 * 64 * 2;     // 48 KB
  off = (off + 255) & ~(size_t)255;
  ushort* X0 = (ushort*)(ws + off);        off += (size_t)N * rowBytes;        // 81.92 MB
  const bool useX0 = (ws_size >= off);
  (void)n_in; (void)out_size;

  dim3 gp((N + 63) / 64, B);
  const int RG = (N + 3) / 4;             // rowgroups of 4 (one wave each)

  wt_prep<<<96, 256, 0, stream>>>(W, Wt_hi, Wt_lo);
  if (useX0) {
    pack_x0<<<2048, 256, 0, stream>>>((const float4*)inp, (uint4*)X0,
                                      (long)B * N * 8);
  }

  for (int s = 0; s < 2; ++s) {
    const int E = in_sizes[s == 0 ? 1 : 4];

    hipMemsetAsync(counts, 0, (size_t)N * 4, stream);
    hist_k<<<(E + 255) / 256, 256, 0, stream>>>(rws[s], counts, E);
    scan_k<<<1, 256, 0, stream>>>(counts, row_ptr, N);
    hipMemsetAsync(counts, 0, (size_t)N * 4, stream);
    fill_k<<<(E + 255) / 256, 256, 0, stream>>>(rws[s], cls[s], vls[s], row_ptr,
                                                counts, euv, E);

    if (useX0) {
      spmm_c<true><<<32 * RG, 256, 0, stream>>>((const uint4*)X0, row_ptr, euv,
                                                (uint4*)X1, N, RG);
    } else {
      spmm1<<<N, 256, 0, stream>>>((const float4*)inp, row_ptr, euv,
                                   (uint2*)X1, N);
    }
    spmm_c<false><<<32 * RG, 256, 0, stream>>>((const uint4*)X1, row_ptr, euv,
                                               (uint4*)X2, N, RG);

    if (s == 0) {
      proj_mfma<false><<<gp, 256, 0, stream>>>((const float4*)inp, (const uint4*)X1,
                                               (const uint4*)X2, Wt_hi, Wt_lo, 0,
                                               bias, out, N);
    } else {
      proj_mfma<true><<<gp, 256, 0, stream>>>((const float4*)inp, (const uint4*)X1,
                                              (const uint4*)X2, Wt_hi, Wt_lo, 3,
                                              bias, out, N);
    }
  }
}

// Round 5
// 1452.305 us; speedup vs baseline: 2.3587x; 1.4168x over previous
//
#include <hip/hip_runtime.h>
#include <hip/hip_fp16.h>

// DiffusionConvolution: out[b,n,o] = bias[o] + sum_{s,k,d} (A_s^k x0)[n,(d,b)] * W[(s*3+k)*64+d, o]
// B=32, N=20000, D=OUT=64, K=2, E=640000 per support.
//
// R8 structure (chunked SpMM, L2-resident slabs, NO cross-lane reduce):
//   X0/X1/X2 in BLOCKED layout X[b][n][64 feats] — per-b slab = N*128 B = 2.56 MB < 4 MB L2.
//   spmm_c: thread owns (row n, uint4 feat-slice q); sequential 4-deep-unrolled edge loop.
//     R7's 8-slot butterfly (48 DS ops/lane/wave ≈ 300 µs serialized) is eliminated.
//     1-D grid XCD-pinned: xcd=i&7, c = xcd + 8*(j/RB), rowgroup = j%RB (32 rows/block).
//   proj_mfma: MFMA 16x16x32 bf16 GEMM (split-bf16 W; j=0 split-bf16 A from fp32 inp).
// Workspace: X1 82 + X2 82 + euv 5.1 + ptr/counts 0.2 + Wt 0.2 + X0 82 = ~252 MB.

constexpr int B = 32;
constexpr int D = 64;
constexpr int C = B * D;   // 2048 features per node

typedef short bf16x8 __attribute__((ext_vector_type(8)));
typedef float f32x4 __attribute__((ext_vector_type(4)));

__device__ __forceinline__ void fma4(float4& a, float s, const float4 b) {
  a.x = fmaf(s, b.x, a.x);
  a.y = fmaf(s, b.y, a.y);
  a.z = fmaf(s, b.z, a.z);
  a.w = fmaf(s, b.w, a.w);
}

__device__ __forceinline__ unsigned f2bf(float f) {
  union { float f; unsigned u; } v; v.f = f;
  return (v.u + 0x7fffu + ((v.u >> 16) & 1u)) >> 16;   // RNE
}
__device__ __forceinline__ unsigned pk(float a, float b) {
  return f2bf(a) | (f2bf(b) << 16);
}
__device__ __forceinline__ float bflo(unsigned u) { return __uint_as_float(u << 16); }
__device__ __forceinline__ float bfhi(unsigned u) { return __uint_as_float(u & 0xffff0000u); }

__device__ __forceinline__ unsigned pkh(float a, float b) {
  union { __half2 h; unsigned u; } c;
  c.h = __floats2half2_rn(a, b);
  return c.u;
}

__device__ __forceinline__ void fma8(float4& a0, float4& a1, float v, uint4 u) {
  a0.x = fmaf(v, bflo(u.x), a0.x); a0.y = fmaf(v, bfhi(u.x), a0.y);
  a0.z = fmaf(v, bflo(u.y), a0.z); a0.w = fmaf(v, bfhi(u.y), a0.w);
  a1.x = fmaf(v, bflo(u.z), a1.x); a1.y = fmaf(v, bfhi(u.z), a1.y);
  a1.z = fmaf(v, bflo(u.w), a1.z); a1.w = fmaf(v, bfhi(u.w), a1.w);
}

__device__ __forceinline__ void fma8h(float4& a0, float4& a1, float v, uint4 u) {
  union { unsigned u; __half2 h; } c0, c1, c2, c3;
  c0.u = u.x; c1.u = u.y; c2.u = u.z; c3.u = u.w;
  float2 f0 = __half22float2(c0.h);
  float2 f1 = __half22float2(c1.h);
  float2 f2 = __half22float2(c2.h);
  float2 f3 = __half22float2(c3.h);
  a0.x = fmaf(v, f0.x, a0.x); a0.y = fmaf(v, f0.y, a0.y);
  a0.z = fmaf(v, f1.x, a0.z); a0.w = fmaf(v, f1.y, a0.w);
  a1.x = fmaf(v, f2.x, a1.x); a1.y = fmaf(v, f2.y, a1.y);
  a1.z = fmaf(v, f3.x, a1.z); a1.w = fmaf(v, f3.y, a1.w);
}

// ---------------- CSR build ----------------

__global__ __launch_bounds__(256) void hist_k(const int* __restrict__ rows,
                                              int* __restrict__ counts, int E) {
  int e = blockIdx.x * 256 + threadIdx.x;
  if (e < E) atomicAdd(&counts[rows[e]], 1);
}

__global__ __launch_bounds__(256) void scan_k(const int* __restrict__ counts,
                                              int* __restrict__ row_ptr, int N) {
  __shared__ int part[256];
  int t = threadIdx.x;
  int chunk = (N + 255) >> 8;
  int lo = t * chunk; if (lo > N) lo = N;
  int hi = lo + chunk; if (hi > N) hi = N;
  int s = 0;
  for (int i = lo; i < hi; ++i) s += counts[i];
  part[t] = s;
  __syncthreads();
  for (int off = 1; off < 256; off <<= 1) {
    int x = (t >= off) ? part[t - off] : 0;
    __syncthreads();
    part[t] += x;
    __syncthreads();
  }
  int run = part[t] - s;
  for (int i = lo; i < hi; ++i) { row_ptr[i] = run; run += counts[i]; }
  if (t == 255) row_ptr[N] = part[255];
}

__global__ __launch_bounds__(256) void fill_k(const int* __restrict__ rows,
                                              const int* __restrict__ cols,
                                              const float* __restrict__ vals,
                                              const int* __restrict__ row_ptr,
                                              int* __restrict__ cursor,
                                              uint2* __restrict__ euv, int E) {
  int e = blockIdx.x * 256 + threadIdx.x;
  if (e < E) {
    int r = rows[e];
    int pos = row_ptr[r] + atomicAdd(&cursor[r], 1);
    euv[pos] = make_uint2((unsigned)cols[e], __float_as_uint(vals[e]));
  }
}

// ---------------- wt_prep: W fp32 [384][64] -> Wt hi/lo bf16 [6][64 o][64 k] ----------------

__global__ __launch_bounds__(256) void wt_prep(const float* __restrict__ W,
                                               ushort* __restrict__ Whi,
                                               ushort* __restrict__ Wlo) {
  int idx = blockIdx.x * 256 + threadIdx.x;
  if (idx >= 384 * 64) return;
  int g = idx >> 6, o = idx & 63;            // g = s*192 + j*64 + k
  int s = g / 192, rem = g - s * 192;
  int j = rem >> 6, k = rem & 63;
  float v = W[g * 64 + o];
  unsigned hb = f2bf(v);
  float hf = __uint_as_float(hb << 16);
  unsigned lb = f2bf(v - hf);
  int pos = ((s * 3 + j) * 64 + o) * 64 + k;
  Whi[pos] = (ushort)hb;
  Wlo[pos] = (ushort)lb;
}

// ---------------- pack_x0: streaming fp32 -> fp16, identical [b][n][d] index ----------------

__global__ __launch_bounds__(256) void pack_x0(const float4* __restrict__ inp4,
                                               uint4* __restrict__ X0u4, long total) {
  long i = (long)blockIdx.x * 256 + threadIdx.x;
  long stride = (long)gridDim.x * 256;
  for (; i < total; i += stride) {
    float4 v0 = inp4[i * 2];
    float4 v1 = inp4[i * 2 + 1];
    X0u4[i] = make_uint4(pkh(v0.x, v0.y), pkh(v0.z, v0.w),
                         pkh(v1.x, v1.y), pkh(v1.z, v1.w));
  }
}

// ---------------- spmm_c: D = A * S, chunked, thread-sequential edge loop ----------------
// Blocked layout S[b][n][64 feats] 16-bit. Block = 32 rows x one chunk; thread t:
// r = t>>3 (row in block), q = t&7 (uint4 slice). Grid 32*RB blocks, RB=ceil(N/32);
// decode xcd=i&7, c = xcd + 8*(j/RB), rg = j%RB -> chunk slab (2.56 MB) L2-resident per XCD.
// No cross-lane ops; 4-deep unrolled gather loop (4 x 16 B loads in flight/thread).

template <bool HALF>
__global__ __launch_bounds__(256) void spmm_c(const uint4* __restrict__ Su4,
                                              const int* __restrict__ row_ptr,
                                              const uint2* __restrict__ euv,
                                              uint4* __restrict__ Du4,
                                              int N, int RB) {
  int i = blockIdx.x;
  int x = i & 7, j = i >> 3;
  int cg = j / RB, rg = j - cg * RB;
  int c = x + 8 * cg;                      // chunk == batch index b, 0..31
  int t = threadIdx.x;
  int n = rg * 32 + (t >> 3);
  if (n >= N) return;
  int q = t & 7;

  int start = row_ptr[n], end = row_ptr[n + 1];
  const uint4* src = Su4 + (size_t)c * (N * 8) + q;
  float4 a0 = {0.f, 0.f, 0.f, 0.f};
  float4 a1 = {0.f, 0.f, 0.f, 0.f};

  int e = start;
  for (; e + 4 <= end; e += 4) {
    uint2 ev0 = euv[e],     ev1 = euv[e + 1];
    uint2 ev2 = euv[e + 2], ev3 = euv[e + 3];
    uint4 u0 = src[(size_t)ev0.x * 8];
    uint4 u1 = src[(size_t)ev1.x * 8];
    uint4 u2 = src[(size_t)ev2.x * 8];
    uint4 u3 = src[(size_t)ev3.x * 8];
    if (HALF) {
      fma8h(a0, a1, __uint_as_float(ev0.y), u0);
      fma8h(a0, a1, __uint_as_float(ev1.y), u1);
      fma8h(a0, a1, __uint_as_float(ev2.y), u2);
      fma8h(a0, a1, __uint_as_float(ev3.y), u3);
    } else {
      fma8(a0, a1, __uint_as_float(ev0.y), u0);
      fma8(a0, a1, __uint_as_float(ev1.y), u1);
      fma8(a0, a1, __uint_as_float(ev2.y), u2);
      fma8(a0, a1, __uint_as_float(ev3.y), u3);
    }
  }
  for (; e < end; ++e) {
    uint2 ev = euv[e];
    uint4 u = src[(size_t)ev.x * 8];
    if (HALF) fma8h(a0, a1, __uint_as_float(ev.y), u);
    else      fma8(a0, a1, __uint_as_float(ev.y), u);
  }

  Du4[((size_t)c * N + n) * 8 + q] = make_uint4(pk(a0.x, a0.y), pk(a0.z, a0.w),
                                                pk(a1.x, a1.y), pk(a1.z, a1.w));
}

// ---------------- spmm1 (fallback, no-X0 path): fp32 full-row gather, blocked write ----------

__global__ __launch_bounds__(256) void spmm1(const float4* __restrict__ inp4,
                                             const int* __restrict__ row_ptr,
                                             const uint2* __restrict__ euv,
                                             uint2* __restrict__ X1u2, int N) {
  int t = threadIdx.x;
  int n = blockIdx.x;
  float4 acc0 = {0.f, 0.f, 0.f, 0.f};
  float4 acc1 = {0.f, 0.f, 0.f, 0.f};
  int start = row_ptr[n], end = row_ptr[n + 1];
  int b0 = t >> 4;
  const float4* p0 = inp4 + (size_t)b0 * (N * 16) + (t & 15);
  const float4* p1 = inp4 + (size_t)(b0 + 16) * (N * 16) + (t & 15);
  for (int e = start; e < end; ++e) {
    uint2 ev = euv[e];
    float v = __uint_as_float(ev.y);
    fma4(acc0, v, p0[(size_t)ev.x * 16]);
    fma4(acc1, v, p1[(size_t)ev.x * 16]);
  }
  X1u2[((size_t)b0 * N + n) * 16 + (t & 15)] =
      make_uint2(pk(acc0.x, acc0.y), pk(acc0.z, acc0.w));
  X1u2[((size_t)(b0 + 16) * N + n) * 16 + (t & 15)] =
      make_uint2(pk(acc1.x, acc1.y), pk(acc1.z, acc1.w));
}

// ---------------- proj_mfma: out (+)= inp*W0 + X1*W1 + X2*W2 (+bias) via MFMA ----------------
// grid ((N+63)/64, B), 256 threads = 4 waves. Out tile 64n x 64o for batch b.
// X1/X2 blocked [b][n][64]: tile staging reads 8 KB contiguous.
// mfma_f32_16x16x32_bf16 layouts (m89-verified). LDS 16B-block index ^= (row&7).

template <bool ADD>
__global__ __launch_bounds__(256) void proj_mfma(const float4* __restrict__ inp4,
                                                 const uint4* __restrict__ X1u4,
                                                 const uint4* __restrict__ X2u4,
                                                 const ushort* __restrict__ Whi,
                                                 const ushort* __restrict__ Wlo,
                                                 int sj0,   // 3*s
                                                 const float* __restrict__ bias,
                                                 float* __restrict__ out, int N) {
  __shared__ uint4 ldsbuf[2048];       // 32 KB
  char* sAhi = (char*)ldsbuf;          // 8 KB  [64 n][64 k] bf16
  char* sAlo = sAhi + 8192;            // 8 KB  (j==0 only)
  char* sWhi = sAhi + 16384;           // 8 KB  [64 o][64 k] bf16
  char* sWlo = sAhi + 24576;           // 8 KB

  int t = threadIdx.x;
  int lane = t & 63, w = t >> 6;
  int b = blockIdx.y;
  int n0 = blockIdx.x * 64;
  int col = lane & 15, kg = lane >> 4;

  f32x4 acc[4];
  if (ADD) {
#pragma unroll
    for (int c = 0; c < 4; ++c) acc[c] = (f32x4){0.f, 0.f, 0.f, 0.f};
  } else {
#pragma unroll
    for (int c = 0; c < 4; ++c) {
      float bv = bias[c * 16 + col];
      acc[c] = (f32x4){bv, bv, bv, bv};
    }
  }

  for (int j = 0; j < 3; ++j) {
    // ---- stage W slice hi/lo (transposed [o][k], swizzled) ----
    {
      const uint4* srcH = (const uint4*)(Whi + (size_t)(sj0 + j) * 4096);
      const uint4* srcL = (const uint4*)(Wlo + (size_t)(sj0 + j) * 4096);
#pragma unroll
      for (int kk = 0; kk < 2; ++kk) {
        int q = t + 256 * kk;
        int o = q >> 3, x8 = q & 7;
        int doff = o * 128 + ((x8 * 16) ^ ((o & 7) << 4));
        *(uint4*)(sWhi + doff) = srcH[q];
        *(uint4*)(sWlo + doff) = srcL[q];
      }
    }
    // ---- stage A tile ----
    if (j == 0) {
      // inp fp32 -> split bf16 hi+lo
#pragma unroll
      for (int kk = 0; kk < 4; ++kk) {
        int q = t + 256 * kk;
        int r = q >> 4, d4 = q & 15;
        int n = n0 + r;
        float4 v = {0.f, 0.f, 0.f, 0.f};
        if (n < N) v = inp4[((size_t)b * N + n) * 16 + d4];
        unsigned h0 = pk(v.x, v.y), h1 = pk(v.z, v.w);
        float lx = v.x - bflo(h0), ly = v.y - bfhi(h0);
        float lz = v.z - bflo(h1), lw = v.w - bfhi(h1);
        int doff = r * 128 + ((d4 * 8) ^ ((r & 7) << 4));
        *(uint2*)(sAhi + doff) = make_uint2(h0, h1);
        *(uint2*)(sAlo + doff) = make_uint2(pk(lx, ly), pk(lz, lw));
      }
    } else {
      const uint4* Xs = (j == 1) ? X1u4 : X2u4;
#pragma unroll
      for (int kk = 0; kk < 2; ++kk) {
        int q = t + 256 * kk;
        int r = q >> 3, x8 = q & 7;
        int n = n0 + r;
        uint4 u = {0u, 0u, 0u, 0u};
        if (n < N) u = Xs[((size_t)b * N + n) * 8 + x8];
        int doff = r * 128 + ((x8 * 16) ^ ((r & 7) << 4));
        *(uint4*)(sAhi + doff) = u;
      }
    }
    __syncthreads();

    // ---- MFMA: K=64 in 2 chunks of 32 ----
#pragma unroll
    for (int kc = 0; kc < 2; ++kc) {
      int kb = kc * 64 + kg * 16;                 // byte offset of this lane's 8 k's
      int arow = w * 16 + col;
      int aoff = arow * 128 + (kb ^ ((arow & 7) << 4));
      bf16x8 ah = *(const bf16x8*)(sAhi + aoff);
      bf16x8 al;
      if (j == 0) al = *(const bf16x8*)(sAlo + aoff);
#pragma unroll
      for (int c = 0; c < 4; ++c) {
        int wrow = c * 16 + col;
        int woff = wrow * 128 + (kb ^ ((wrow & 7) << 4));
        bf16x8 bh = *(const bf16x8*)(sWhi + woff);
        bf16x8 bl = *(const bf16x8*)(sWlo + woff);
        acc[c] = __builtin_amdgcn_mfma_f32_16x16x32_bf16(ah, bh, acc[c], 0, 0, 0);
        acc[c] = __builtin_amdgcn_mfma_f32_16x16x32_bf16(ah, bl, acc[c], 0, 0, 0);
        if (j == 0)
          acc[c] = __builtin_amdgcn_mfma_f32_16x16x32_bf16(al, bh, acc[c], 0, 0, 0);
      }
    }
    __syncthreads();
  }

  // ---- store: row = n0 + 16w + 4*kg + reg, col = 16c + (lane&15) ----
  int rbase = n0 + w * 16 + kg * 4;
  size_t obase = (size_t)b * N * 64;
#pragma unroll
  for (int c = 0; c < 4; ++c) {
#pragma unroll
    for (int r = 0; r < 4; ++r) {
      int row = rbase + r;
      if (row < N) {
        float* op = out + obase + (size_t)row * 64 + c * 16 + col;
        float vv = acc[c][r];
        if (ADD) *op += vv; else *op = vv;
      }
    }
  }
}

// ---------------- launch ----------------

extern "C" void kernel_launch(void* const* d_in, const int* in_sizes, int n_in,
                              void* d_out, int out_size, void* d_ws, size_t ws_size,
                              hipStream_t stream) {
  const float* inp = (const float*)d_in[0];
  const int*   rws[2] = {(const int*)d_in[1], (const int*)d_in[4]};
  const int*   cls[2] = {(const int*)d_in[2], (const int*)d_in[5]};
  const float* vls[2] = {(const float*)d_in[3], (const float*)d_in[6]};
  const float* W    = (const float*)d_in[7];
  const float* bias = (const float*)d_in[8];
  float* out = (float*)d_out;

  const int N = in_sizes[0] / C;          // 20000
  const int Emax = (in_sizes[1] > in_sizes[4]) ? in_sizes[1] : in_sizes[4];

  // workspace layout: X1, X2, euv, ptr/counts, Wt hi/lo, then X0 fp16 tail (guarded)
  char* ws = (char*)d_ws;
  size_t rowBytes = (size_t)C * 2;                        // 4096 B/node (bf16 or fp16)
  ushort* X1 = (ushort*)ws;                size_t off = (size_t)N * rowBytes;  // 81.92 MB
  ushort* X2 = (ushort*)(ws + off);        off += (size_t)N * rowBytes;        // 81.92 MB
  uint2* euv = (uint2*)(ws + off);         off += (size_t)Emax * 8;
  int*   row_ptr = (int*)(ws + off);       off += (size_t)(N + 1) * 4;
  off = (off + 255) & ~(size_t)255;
  int*   counts = (int*)(ws + off);        off += (size_t)N * 4;
  off = (off + 255) & ~(size_t)255;
  ushort* Wt_hi = (ushort*)(ws + off);     off += (size_t)6 * 64 * 64 * 2;     // 48 KB
  ushort* Wt_lo = (ushort*)(ws + off);     off += (size_t)6 * 64 * 64 * 2;     // 48 KB
  off = (off + 255) & ~(size_t)255;
  ushort* X0 = (ushort*)(ws + off);        off += (size_t)N * rowBytes;        // 81.92 MB
  const bool useX0 = (ws_size >= off);
  (void)n_in; (void)out_size;

  dim3 gp((N + 63) / 64, B);
  const int RB = (N + 31) / 32;           // rowgroups of 32 (one block each)

  wt_prep<<<96, 256, 0, stream>>>(W, Wt_hi, Wt_lo);
  if (useX0) {
    pack_x0<<<2048, 256, 0, stream>>>((const float4*)inp, (uint4*)X0,
                                      (long)B * N * 8);
  }

  for (int s = 0; s < 2; ++s) {
    const int E = in_sizes[s == 0 ? 1 : 4];

    hipMemsetAsync(counts, 0, (size_t)N * 4, stream);
    hist_k<<<(E + 255) / 256, 256, 0, stream>>>(rws[s], counts, E);
    scan_k<<<1, 256, 0, stream>>>(counts, row_ptr, N);
    hipMemsetAsync(counts, 0, (size_t)N * 4, stream);
    fill_k<<<(E + 255) / 256, 256, 0, stream>>>(rws[s], cls[s], vls[s], row_ptr,
                                                counts, euv, E);

    if (useX0) {
      spmm_c<true><<<32 * RB, 256, 0, stream>>>((const uint4*)X0, row_ptr, euv,
                                                (uint4*)X1, N, RB);
    } else {
      spmm1<<<N, 256, 0, stream>>>((const float4*)inp, row_ptr, euv,
                                   (uint2*)X1, N);
    }
    spmm_c<false><<<32 * RB, 256, 0, stream>>>((const uint4*)X1, row_ptr, euv,
                                               (uint4*)X2, N, RB);

    if (s == 0) {
      proj_mfma<false><<<gp, 256, 0, stream>>>((const float4*)inp, (const uint4*)X1,
                                               (const uint4*)X2, Wt_hi, Wt_lo, 0,
                                               bias, out, N);
    } else {
      proj_mfma<true><<<gp, 256, 0, stream>>>((const float4*)inp, (const uint4*)X1,
                                              (const uint4*)X2, Wt_hi, Wt_lo, 3,
                                              bias, out, N);
    }
  }
}